// Round 1
// baseline (316.911 us; speedup 1.0000x reference)
//
#include <hip/hip_runtime.h>
#include <hip/hip_bf16.h>
#include <math.h>

// Problem: Caffe-style RPN proposal layer.
// scores: (1,64,64,18) f32, bbox_deltas: (1,64,64,36) f32 -> out (300,4) f32.
// N = 64*64*9 = 36864 anchors, top-6000 by masked score (tie: lower index),
// greedy NMS IoU>0.5 (+1 box convention), first 300 kept, /1024.

#define NPROP   36864
#define SORT_M  65536
#define TOPN    6000
#define POSTN   300
#define NWORDS  94          // ceil(6000/64)

// classic 9 anchors for base=16, ratios {0.5,1,2}, scales {8,16,32}
__constant__ float ANCH[9][4] = {
    {-84.f,  -40.f,  99.f,  55.f},
    {-176.f, -88.f,  191.f, 103.f},
    {-360.f, -184.f, 375.f, 199.f},
    {-56.f,  -56.f,  71.f,  71.f},
    {-120.f, -120.f, 135.f, 135.f},
    {-248.f, -248.f, 263.f, 263.f},
    {-36.f,  -80.f,  51.f,  95.f},
    {-80.f,  -168.f, 95.f,  183.f},
    {-168.f, -344.f, 183.f, 359.f},
};

__global__ void decode_kernel(const float* __restrict__ scores,
                              const float* __restrict__ deltas,
                              float4* __restrict__ boxes,
                              unsigned long long* __restrict__ keys) {
    int i = blockIdx.x * blockDim.x + threadIdx.x;
    if (i >= SORT_M) return;
    if (i >= NPROP) { keys[i] = 0ULL; return; }  // padding: smallest key

    int a   = i % 9;
    int pos = i / 9;
    int wx = pos & 63, hy = pos >> 6;
    float sx = (float)(wx * 16), sy = (float)(hy * 16);

    float ax1 = ANCH[a][0] + sx, ay1 = ANCH[a][1] + sy;
    float ax2 = ANCH[a][2] + sx, ay2 = ANCH[a][3] + sy;
    float aw  = ax2 - ax1 + 1.0f;   // exact integers
    float ah  = ay2 - ay1 + 1.0f;
    float acx = ax1 + 0.5f * aw;
    float acy = ay1 + 0.5f * ah;

    const float* d = deltas + ((size_t)pos * 36 + a * 4);
    float dx = d[0], dy = d[1], dw = d[2], dh = d[3];
    float fg = scores[(size_t)pos * 18 + 9 + a];

    // match unfused numpy rounding: no FMA contraction
    float pcx = __fadd_rn(__fmul_rn(dx, aw), acx);
    float pcy = __fadd_rn(__fmul_rn(dy, ah), acy);
    float pw  = __fmul_rn(expf(dw), aw);
    float ph  = __fmul_rn(expf(dh), ah);
    float hx  = __fmul_rn(0.5f, pw);
    float hv  = __fmul_rn(0.5f, ph);

    float x1 = fminf(fmaxf(__fsub_rn(pcx, hx), 0.0f), 1023.0f);
    float y1 = fminf(fmaxf(__fsub_rn(pcy, hv), 0.0f), 1023.0f);
    float x2 = fminf(fmaxf(__fadd_rn(pcx, hx), 0.0f), 1023.0f);
    float y2 = fminf(fmaxf(__fadd_rn(pcy, hv), 0.0f), 1023.0f);

    float bw = __fadd_rn(__fsub_rn(x2, x1), 1.0f);
    float bh = __fadd_rn(__fsub_rn(y2, y1), 1.0f);
    bool valid = (bw >= 16.0f) && (bh >= 16.0f);
    float sc = valid ? fg : -__builtin_huge_valf();

    boxes[i] = make_float4(x1, y1, x2, y2);

    unsigned u = __float_as_uint(sc);
    u = (u & 0x80000000u) ? ~u : (u | 0x80000000u);   // sortable: bigger = better
    keys[i] = ((unsigned long long)u << 32) |
              (unsigned long long)(0xFFFFFFFFu - (unsigned)i); // tie: lower idx first
}

// ---------- bitonic sort (descending) of SORT_M u64 keys ----------
__global__ __launch_bounds__(1024) void bitonic_local(unsigned long long* __restrict__ keys) {
    __shared__ unsigned long long s[2048];
    int t = threadIdx.x;
    int base = blockIdx.x * 2048;
    s[t]        = keys[base + t];
    s[t + 1024] = keys[base + t + 1024];
    __syncthreads();
    for (int k = 2; k <= 2048; k <<= 1) {
        for (int j = k >> 1; j >= 1; j >>= 1) {
            int li = ((t & ~(j - 1)) << 1) | (t & (j - 1));
            int lj = li | j;
            int gi = base + li;
            bool desc = ((gi & k) == 0);
            unsigned long long a = s[li], b = s[lj];
            bool sw = desc ? (a < b) : (a > b);
            if (sw) { s[li] = b; s[lj] = a; }
            __syncthreads();
        }
    }
    keys[base + t]        = s[t];
    keys[base + t + 1024] = s[t + 1024];
}

__global__ void bitonic_global(unsigned long long* __restrict__ keys, int j, int k) {
    int t = blockIdx.x * blockDim.x + threadIdx.x;   // SORT_M/2 threads
    int i = ((t & ~(j - 1)) << 1) | (t & (j - 1));
    int l = i | j;
    unsigned long long a = keys[i], b = keys[l];
    bool desc = ((i & k) == 0);
    bool sw = desc ? (a < b) : (a > b);
    if (sw) { keys[i] = b; keys[l] = a; }
}

__global__ __launch_bounds__(1024) void bitonic_merge_local(unsigned long long* __restrict__ keys, int k) {
    __shared__ unsigned long long s[2048];
    int t = threadIdx.x;
    int base = blockIdx.x * 2048;
    s[t]        = keys[base + t];
    s[t + 1024] = keys[base + t + 1024];
    __syncthreads();
    for (int j = 1024; j >= 1; j >>= 1) {
        int li = ((t & ~(j - 1)) << 1) | (t & (j - 1));
        int lj = li | j;
        int gi = base + li;
        bool desc = ((gi & k) == 0);
        unsigned long long a = s[li], b = s[lj];
        bool sw = desc ? (a < b) : (a > b);
        if (sw) { s[li] = b; s[lj] = a; }
        __syncthreads();
    }
    keys[base + t]        = s[t];
    keys[base + t + 1024] = s[t + 1024];
}

// ---------- gather top-6000 boxes + areas ----------
__global__ void gather_top(const unsigned long long* __restrict__ keys,
                           const float4* __restrict__ boxes,
                           float4* __restrict__ top,
                           float* __restrict__ areas) {
    int t = blockIdx.x * blockDim.x + threadIdx.x;
    if (t >= TOPN) return;
    unsigned long long key = keys[t];
    unsigned idx = 0xFFFFFFFFu - (unsigned)(key & 0xFFFFFFFFull);
    float4 b = boxes[idx];
    top[t] = b;
    areas[t] = __fmul_rn(__fadd_rn(__fsub_rn(b.z, b.x), 1.0f),
                         __fadd_rn(__fsub_rn(b.w, b.y), 1.0f));
}

// ---------- NMS suppression bit-matrix (j > i only) ----------
__global__ void nms_mask(const float4* __restrict__ boxes,
                         const float* __restrict__ areas,
                         unsigned long long* __restrict__ mask) {
    __shared__ float4 cbx[64];
    __shared__ float  car[64];
    int rb = blockIdx.x, cb = blockIdx.y;
    int tid = threadIdx.x;
    int j0 = cb * 64;
    if (j0 + tid < TOPN) { cbx[tid] = boxes[j0 + tid]; car[tid] = areas[j0 + tid]; }
    __syncthreads();
    int i = rb * 64 + tid;
    if (i >= TOPN) return;
    float4 bi = boxes[i];
    float  ai = areas[i];
    unsigned long long bits = 0ULL;
    int jmax = min(64, TOPN - j0);
    for (int jj = 0; jj < jmax; ++jj) {
        int j = j0 + jj;
        if (j <= i) continue;
        float4 bj = cbx[jj];
        float xx1 = fmaxf(bi.x, bj.x);
        float yy1 = fmaxf(bi.y, bj.y);
        float xx2 = fminf(bi.z, bj.z);
        float yy2 = fminf(bi.w, bj.w);
        float w = fmaxf(__fadd_rn(__fsub_rn(xx2, xx1), 1.0f), 0.0f);
        float h = fmaxf(__fadd_rn(__fsub_rn(yy2, yy1), 1.0f), 0.0f);
        float inter = __fmul_rn(w, h);
        float denom = __fsub_rn(__fadd_rn(ai, car[jj]), inter);
        float iou = inter / denom;
        if (iou > 0.5f) bits |= (1ULL << jj);
    }
    mask[(size_t)i * NWORDS + cb] = bits;
}

// ---------- sequential greedy scan: one wave, 64 lanes ----------
// Lane l owns removed-words l and l+64. -inf boxes participate in suppression
// but are excluded from output (keep & isfinite applied AFTER NMS in ref).
__global__ void nms_seq(const unsigned long long* __restrict__ keys,
                        const unsigned long long* __restrict__ mask,
                        int* __restrict__ kept, int* __restrict__ count_out) {
    int lane = threadIdx.x;  // 0..63
    unsigned long long rem0 = 0ULL, rem1 = 0ULL;
    int cnt = 0;
    for (int i = 0; i < TOPN && cnt < POSTN; ++i) {
        int word = i >> 6, bit = i & 63;
        int owner = (word < 64) ? word : (word - 64);
        unsigned long long my = (word < 64) ? rem0 : rem1;
        unsigned long long rw = __shfl(my, owner, 64);
        bool removed = (rw >> bit) & 1ULL;
        if (!removed) {
            rem0 |= mask[(size_t)i * NWORDS + lane];
            if (lane + 64 < NWORDS) rem1 |= mask[(size_t)i * NWORDS + lane + 64];
            unsigned sp = (unsigned)(keys[i] >> 32);
            bool finite = (sp != 0x007FFFFFu);   // -inf sortable pattern
            if (finite) {
                if (lane == 0) kept[cnt] = i;
                ++cnt;
            }
        }
    }
    if (lane == 0) *count_out = cnt;
}

__global__ void write_out(const float4* __restrict__ top,
                          const int* __restrict__ kept,
                          const int* __restrict__ count,
                          float* __restrict__ out) {
    int t = blockIdx.x * blockDim.x + threadIdx.x;
    if (t >= POSTN) return;
    int c = *count;
    float x = 0.f, y = 0.f, z = 0.f, w = 0.f;
    if (t < c) {
        float4 v = top[kept[t]];
        x = v.x / 1024.0f; y = v.y / 1024.0f; z = v.z / 1024.0f; w = v.w / 1024.0f;
    }
    out[t * 4 + 0] = x;
    out[t * 4 + 1] = y;
    out[t * 4 + 2] = z;
    out[t * 4 + 3] = w;
}

extern "C" void kernel_launch(void* const* d_in, const int* in_sizes, int n_in,
                              void* d_out, int out_size, void* d_ws, size_t ws_size,
                              hipStream_t stream) {
    const float* scores = (const float*)d_in[0];   // (1,64,64,18)
    const float* deltas = (const float*)d_in[1];   // (1,64,64,36)
    float* out = (float*)d_out;                    // 300*4

    char* w = (char*)d_ws;
    float4*              boxes = (float4*)(w);                     // 589824 B
    unsigned long long*  keys  = (unsigned long long*)(w + 589824);// 524288 B
    float4*              topb  = (float4*)(w + 1114112);           // 96000 B
    float*               areas = (float*)(w + 1210112);            // 24000 B
    unsigned long long*  mask  = (unsigned long long*)(w + 1234112); // 4512000 B
    int*                 kept  = (int*)(w + 5746112);              // 1200 B
    int*                 cnt   = (int*)(w + 5747312);              // 4 B

    decode_kernel<<<SORT_M / 256, 256, 0, stream>>>(scores, deltas, boxes, keys);

    bitonic_local<<<SORT_M / 2048, 1024, 0, stream>>>(keys);
    for (int k = 4096; k <= SORT_M; k <<= 1) {
        for (int j = k >> 1; j >= 2048; j >>= 1)
            bitonic_global<<<SORT_M / 2 / 256, 256, 0, stream>>>(keys, j, k);
        bitonic_merge_local<<<SORT_M / 2048, 1024, 0, stream>>>(keys, k);
    }

    gather_top<<<(TOPN + 255) / 256, 256, 0, stream>>>(keys, boxes, topb, areas);
    nms_mask<<<dim3(NWORDS, NWORDS), 64, 0, stream>>>(topb, areas, mask);
    nms_seq<<<1, 64, 0, stream>>>(keys, mask, kept, cnt);
    write_out<<<1, 320, 0, stream>>>(topb, kept, cnt, out);
}